// Round 16
// baseline (86.750 us; speedup 1.0000x reference)
//
#include <hip/hip_runtime.h>
#include <climits>

using short8 = __attribute__((ext_vector_type(8))) short;
using f32x4  = __attribute__((ext_vector_type(4))) float;
typedef _Float16 half8 __attribute__((ext_vector_type(8)));
typedef unsigned short u16;

#define BATCH 8192
#define TDIM  384
#define GDIM  256

// ---------- helpers ----------
__device__ __forceinline__ u16 f2bf(float x) {
  unsigned u = __float_as_uint(x);
  unsigned r = (u + 0x7FFFu + ((u >> 16) & 1u)) >> 16;  // RTNE
  return (u16)r;
}

__device__ __forceinline__ void gload16(u16* lds, const u16* src) {
  __builtin_amdgcn_global_load_lds(
      (const __attribute__((address_space(1))) void*)src,
      (__attribute__((address_space(3))) void*)lds, 16, 0, 0);
}

// ---------- 1. fused prep: text->fp16-normalized, graph/W->bf16, partial init ----
__global__ void prep_all(const float* __restrict__ text, const float* __restrict__ graph,
                         const float* __restrict__ W, u16* __restrict__ tH,
                         u16* __restrict__ gHi, u16* __restrict__ wHi,
                         int* __restrict__ pMax, int* __restrict__ pMin) {
  const int b = blockIdx.x;
  if (b < 4096) {  // init 128x8192 partial keys
    const int i = b * 256 + threadIdx.x;
    pMax[i] = INT_MIN;
    pMin[i] = INT_MAX;
  }
  if (b < 2048) {
    const int lane = threadIdx.x & 63;
    const int wid  = threadIdx.x >> 6;
    const int row  = b * 4 + wid;
    const float* x = text + row * TDIM;
    float v[6];
    float ss = 0.f;
#pragma unroll
    for (int q = 0; q < 6; ++q) { v[q] = x[lane + q * 64]; ss += v[q] * v[q]; }
#pragma unroll
    for (int m = 1; m < 64; m <<= 1) ss += __shfl_xor(ss, m);
    const float scale = 1.0f / fmaxf(sqrtf(ss), 1e-12f);
#pragma unroll
    for (int q = 0; q < 6; ++q) {
      _Float16 h = (_Float16)(v[q] * scale);
      tH[row * TDIM + lane + q * 64] = *(u16*)&h;
    }
  } else {
    const int i = (b - 2048) * 256 + threadIdx.x;
    if (i < 524288) {
      float4 v = ((const float4*)graph)[i];
      ushort4 o; o.x = f2bf(v.x); o.y = f2bf(v.y); o.z = f2bf(v.z); o.w = f2bf(v.w);
      ((ushort4*)gHi)[i] = o;
    } else {
      int j = i - 524288;
      if (j < 24576) {
        float4 v = ((const float4*)W)[j];
        ushort4 o; o.x = f2bf(v.x); o.y = f2bf(v.y); o.z = f2bf(v.z); o.w = f2bf(v.w);
        ((ushort4*)wHi)[j] = o;
      }
    }
  }
}

// ---------- 2. fused simk + gemm1 ----------
// Sim epilogue restructured for minimal live registers: each key is folded,
// shuffle-reduced, and LDS-atomicMax/Min'd immediately (2 live ints) -- no
// keyMax[16] arrays, no scratch spill. Final partial store is one coalesced
// 512B run per direction in p[chunk][row] layout (line-exclusive per block).
__global__ __launch_bounds__(256, 4) void simgemm(const u16* __restrict__ tH,
                                                  const u16* __restrict__ gHi,
                                                  const u16* __restrict__ wHi,
                                                  const float* __restrict__ bias,
                                                  float* __restrict__ g,
                                                  int* __restrict__ pMax,
                                                  int* __restrict__ pMin) {
  __shared__ u16 sA[8192];   // sim: 128 rows x 64 | gemm: 128 x 32 (half used)
  __shared__ u16 sB[8192];
  const int tid = threadIdx.x;
  const int lane = tid & 63, wid = tid >> 6;
  const int l15 = lane & 15, l4 = lane >> 4;
  const int wrb = (wid >> 1) * 64, wcb = (wid & 1) * 64;

  if (blockIdx.x < 192) {
    // ================= gemm1 path =================
    const int iBase = (blockIdx.x & 63) * 128, jBase = (blockIdx.x >> 6) * 128;
    const int sRow = tid >> 2, sS = (tid & 3) * 8;
    f32x4 acc[4][4];
#pragma unroll
    for (int i = 0; i < 4; ++i)
#pragma unroll
      for (int j = 0; j < 4; ++j) acc[i][j] = (f32x4){0.f, 0.f, 0.f, 0.f};

    for (int ks = 0; ks < GDIM / 32; ++ks) {
      const int kB = ks * 32;
      __syncthreads();
      gload16(&sA[tid * 8],        gHi + (size_t)(iBase + sRow) * GDIM + kB + sS);
      gload16(&sA[2048 + tid * 8], gHi + (size_t)(iBase + 64 + sRow) * GDIM + kB + sS);
      gload16(&sB[tid * 8],        wHi + (size_t)(jBase + sRow) * GDIM + kB + sS);
      gload16(&sB[2048 + tid * 8], wHi + (size_t)(jBase + 64 + sRow) * GDIM + kB + sS);
      __syncthreads();
      short8 a[4], b[4];
#pragma unroll
      for (int f = 0; f < 4; ++f) {
        a[f] = *(const short8*)&sA[(wrb + f * 16 + l15) * 32 + l4 * 8];
        b[f] = *(const short8*)&sB[(wcb + f * 16 + l15) * 32 + l4 * 8];
      }
#pragma unroll
      for (int i = 0; i < 4; ++i)
#pragma unroll
        for (int j = 0; j < 4; ++j)
          acc[i][j] = __builtin_amdgcn_mfma_f32_16x16x32_bf16(a[i], b[j], acc[i][j], 0, 0, 0);
    }
#pragma unroll
    for (int j = 0; j < 4; ++j) {
      const int col = jBase + wcb + j * 16 + l15;
      const float bv = bias[col];
#pragma unroll
      for (int i = 0; i < 4; ++i)
#pragma unroll
        for (int r = 0; r < 4; ++r) {
          const int row = iBase + wrb + i * 16 + l4 * 4 + r;
          g[(size_t)row * TDIM + col] = acc[i][j][r] + bv;
        }
    }
    return;
  }

  // ================= sim path =================
  const int b = blockIdx.x - 192;
  const int id = (b & 7) * 260 + (b >> 3);     // XCD-chunked bijective (2080 = 8*260)

  // supertile-major decode (8x8-panel supertiles over 64 panels)
  int SI = 0, rem = id;
  for (; SI < 8; ++SI) {
    const int rc = 36 + (7 - SI) * 64;
    if (rem < rc) break;
    rem -= rc;
  }
  int bi, bj;
  if (rem < 36) {            // diagonal supertile: upper-tri 8x8
    int li = 0, r2 = rem;
    for (; li < 8; ++li) { const int c = 8 - li; if (r2 < c) break; r2 -= c; }
    bi = SI * 8 + li;
    bj = SI * 8 + li + r2;
  } else {                   // off-diagonal supertile: full 8x8
    const int r2 = rem - 36;
    const int sj = SI + 1 + (r2 >> 6);
    const int l = r2 & 63;
    bi = SI * 8 + (l >> 3);
    bj = sj * 8 + (l & 7);
  }
  const int rBase = bi * 128, cBase = bj * 128;
  const bool diagT = (bi == bj);

  const int sR = tid >> 3;                      // staging row 0..31
  const int ch = tid & 7;                       // staging chunk 0..7
  const int cg = ((ch ^ (sR & 7)) * 8);         // pre-swizzled source col offset
  const u16* aS = tH + (size_t)rBase * TDIM;
  const u16* bS = tH + (size_t)cBase * TDIM;

  f32x4 acc[4][4];
#pragma unroll
  for (int i = 0; i < 4; ++i)
#pragma unroll
    for (int j = 0; j < 4; ++j) acc[i][j] = (f32x4){0.f, 0.f, 0.f, 0.f};

  for (int t = 0; t < 6; ++t) {
    const int kB = t * 64;
    __syncthreads();   // prior step's ds_reads done -> safe to overwrite
#pragma unroll
    for (int r = 0; r < 4; ++r) {
      gload16(&sA[r * 2048 + tid * 8], aS + (size_t)(sR + 32 * r) * TDIM + kB + cg);
      gload16(&sB[r * 2048 + tid * 8], bS + (size_t)(sR + 32 * r) * TDIM + kB + cg);
    }
    __syncthreads();   // drains vmcnt(0): staged data visible

#pragma unroll
    for (int kk = 0; kk < 2; ++kk) {
      half8 a[4], b8[4];
#pragma unroll
      for (int f = 0; f < 4; ++f) {
        const int ar = wrb + f * 16 + l15;
        const int br = wcb + f * 16 + l15;
        a[f]  = *(const half8*)&sA[ar * 64 + (((kk * 4 + l4) ^ (ar & 7)) * 8)];
        b8[f] = *(const half8*)&sB[br * 64 + (((kk * 4 + l4) ^ (br & 7)) * 8)];
      }
      __builtin_amdgcn_s_setprio(1);
#pragma unroll
      for (int i = 0; i < 4; ++i)
#pragma unroll
        for (int j = 0; j < 4; ++j)
          acc[i][j] = __builtin_amdgcn_mfma_f32_16x16x32_f16(a[i], b8[j], acc[i][j], 0, 0, 0);
      __builtin_amdgcn_s_setprio(0);
    }
  }

  // ---- slim epilogue: merge buffers aliased on staging LDS ----
  int* sMd = (int*)&sA[0];     // [128] direct max
  int* sNd = (int*)&sA[256];   // [128] direct min
  int* sMt = (int*)&sA[512];   // [128] transposed max
  int* sNt = (int*)&sA[768];   // [128] transposed min

  __syncthreads();  // all waves past LDS staging reads -> safe to reuse sA
  if (tid < 128) {
    sMd[tid] = INT_MIN; sNd[tid] = INT_MAX;
  } else {
    sMt[tid - 128] = INT_MIN; sNt[tid - 128] = INT_MAX;
  }
  __syncthreads();

  // direct keys: per (i,r) fold j's -> 16-lane reduce -> one LDS atomic
#pragma unroll
  for (int i = 0; i < 4; ++i)
#pragma unroll
    for (int r = 0; r < 4; ++r) {
      const int grow = rBase + wrb + i * 16 + l4 * 4 + r;
      int km = INT_MIN, kn = INT_MAX;
#pragma unroll
      for (int j = 0; j < 4; ++j) {
        const int cIdx = cBase + wcb + j * 16 + l15;
        const int qv = (int)(acc[i][j][r] * 131072.0f);
        int kmv = qv * 8192 + (8191 - cIdx);
        int knv = qv * 8192 + cIdx;
        if (diagT && grow == cIdx) { kmv = 8191 - cIdx; knv = INT_MAX; }
        km = max(km, kmv);
        kn = min(kn, knv);
      }
#pragma unroll
      for (int m = 1; m < 16; m <<= 1) {
        km = max(km, __shfl_xor(km, m));
        kn = min(kn, __shfl_xor(kn, m));
      }
      if (l15 == 0) {
        atomicMax(&sMd[wrb + i * 16 + l4 * 4 + r], km);
        atomicMin(&sNd[wrb + i * 16 + l4 * 4 + r], kn);
      }
    }

  // transposed keys: per j fold (i,r) -> 4-group reduce -> one LDS atomic
#pragma unroll
  for (int j = 0; j < 4; ++j) {
    const int cIdx = cBase + wcb + j * 16 + l15;
    int km = INT_MIN, kn = INT_MAX;
#pragma unroll
    for (int i = 0; i < 4; ++i)
#pragma unroll
      for (int r = 0; r < 4; ++r) {
        const int grow = rBase + wrb + i * 16 + l4 * 4 + r;
        const int qv = (int)(acc[i][j][r] * 131072.0f);
        int kmv = qv * 8192 + (8191 - grow);
        int knv = qv * 8192 + grow;
        if (diagT && grow == cIdx) { kmv = 8191 - grow; knv = INT_MAX; }
        km = max(km, kmv);
        kn = min(kn, knv);
      }
    km = max(km, __shfl_xor(km, 16)); kn = min(kn, __shfl_xor(kn, 16));
    km = max(km, __shfl_xor(km, 32)); kn = min(kn, __shfl_xor(kn, 32));
    if (l4 == 0) {
      atomicMax(&sMt[wcb + j * 16 + l15], km);
      atomicMin(&sNt[wcb + j * 16 + l15], kn);
    }
  }
  __syncthreads();

  // coalesced line-exclusive store: p[chunk][row], 512B run per direction
  if (tid < 128) {
    pMax[(size_t)bj * BATCH + rBase + tid] = sMd[tid];
    pMin[(size_t)bj * BATCH + rBase + tid] = sNd[tid];
  } else {
    const int t2 = tid - 128;
    pMax[(size_t)(64 + bi) * BATCH + cBase + t2] = sMt[t2];
    pMin[(size_t)(64 + bi) * BATCH + cBase + t2] = sNt[t2];
  }
}

// ---------- 3. merge partials + per-row triplet loss from raw g ----------
__global__ void loss_rows(const float* __restrict__ g, const int* __restrict__ pMax,
                          const int* __restrict__ pMin, float* __restrict__ losses) {
  const int lane = threadIdx.x & 63;
  const int wid  = threadIdx.x >> 6;
  const int row  = blockIdx.x * 4 + wid;
  int km = max(pMax[(size_t)lane * BATCH + row], pMax[(size_t)(64 + lane) * BATCH + row]);
  int kn = min(pMin[(size_t)lane * BATCH + row], pMin[(size_t)(64 + lane) * BATCH + row]);
#pragma unroll
  for (int m = 1; m < 64; m <<= 1) {
    km = max(km, __shfl_xor(km, m));
    kn = min(kn, __shfl_xor(kn, m));
  }
  const int pos = 8191 - (km & 8191);
  const int neg = kn & 8191;
  const float* ga = g + (size_t)row * TDIM;
  const float* gp = g + (size_t)pos * TDIM;
  const float* gn = g + (size_t)neg * TDIM;
  float ssa = 0.f, ssp = 0.f, ssn = 0.f, dap = 0.f, dan = 0.f;
#pragma unroll
  for (int q = 0; q < 6; ++q) {
    const int o = lane + q * 64;
    const float a = ga[o], p = gp[o], n = gn[o];
    ssa += a * a; ssp += p * p; ssn += n * n;
    dap += a * p; dan += a * n;
  }
#pragma unroll
  for (int m = 1; m < 64; m <<= 1) {
    ssa += __shfl_xor(ssa, m);
    ssp += __shfl_xor(ssp, m);
    ssn += __shfl_xor(ssn, m);
    dap += __shfl_xor(dap, m);
    dan += __shfl_xor(dan, m);
  }
  if (lane == 0) {
    const float pd = 2.0f - 2.0f * dap / sqrtf(ssa * ssp);
    const float nd = 2.0f - 2.0f * dan / sqrtf(ssa * ssn);
    losses[row] = fmaxf(pd - nd + 0.5f, 0.0f);
  }
}

// ---------- 4. deterministic mean ----------
__global__ void final_reduce(const float* __restrict__ losses, float* __restrict__ out) {
  __shared__ float red[256];
  float s = 0.f;
  for (int i = threadIdx.x; i < BATCH; i += 256) s += losses[i];
  red[threadIdx.x] = s;
  __syncthreads();
  for (int w = 128; w > 0; w >>= 1) {
    if (threadIdx.x < w) red[threadIdx.x] += red[threadIdx.x + w];
    __syncthreads();
  }
  if (threadIdx.x == 0) out[0] = red[0] * (1.0f / (float)BATCH);
}

extern "C" void kernel_launch(void* const* d_in, const int* in_sizes, int n_in,
                              void* d_out, int out_size, void* d_ws, size_t ws_size,
                              hipStream_t stream) {
  const float* graph = (const float*)d_in[0];
  const float* text  = (const float*)d_in[1];
  const float* W     = (const float*)d_in[2];
  const float* bias  = (const float*)d_in[3];
  float* out = (float*)d_out;
  char* ws = (char*)d_ws;

  u16*  tH     = (u16*)(ws);                 // 8192*384*2  = 6291456
  u16*  gHi    = (u16*)(ws + 6291456);       // 8192*256*2  = 4194304
  u16*  wHi    = (u16*)(ws + 10485760);      // 384*256*2   = 196608
  float* g     = (float*)(ws + 10682368);    // 8192*384*4  = 12582912
  int*  pMax   = (int*)(ws + 23265280);      // 128*8192*4  = 4194304
  int*  pMin   = (int*)(ws + 27459584);      // 4194304
  float* losses = (float*)(ws + 31653888);   // 32768

  prep_all<<<dim3(4192), dim3(256), 0, stream>>>(text, graph, W, tH, gHi, wHi, pMax, pMin);
  simgemm<<<dim3(2272), dim3(256), 0, stream>>>(tH, gHi, wHi, bias, g, pMax, pMin);
  loss_rows<<<dim3(2048), dim3(256), 0, stream>>>(g, pMax, pMin, losses);
  final_reduce<<<dim3(1), dim3(256), 0, stream>>>(losses, out);
}

// Round 17
// 79.290 us; speedup vs baseline: 1.0941x; 1.0941x over previous
//
#include <hip/hip_runtime.h>
#include <climits>

using short8 = __attribute__((ext_vector_type(8))) short;
using f32x4  = __attribute__((ext_vector_type(4))) float;
typedef _Float16 half8 __attribute__((ext_vector_type(8)));
typedef unsigned short u16;

#define BATCH 8192
#define TDIM  384
#define GDIM  256

// ---------- helpers ----------
__device__ __forceinline__ u16 f2bf(float x) {
  unsigned u = __float_as_uint(x);
  unsigned r = (u + 0x7FFFu + ((u >> 16) & 1u)) >> 16;  // RTNE
  return (u16)r;
}

__device__ __forceinline__ void gload16(u16* lds, const u16* src) {
  __builtin_amdgcn_global_load_lds(
      (const __attribute__((address_space(1))) void*)src,
      (__attribute__((address_space(3))) void*)lds, 16, 0, 0);
}

// ---------- 1. fused prep: text->fp16-normalized, graph/W->bf16, partial init ----
__global__ void prep_all(const float* __restrict__ text, const float* __restrict__ graph,
                         const float* __restrict__ W, u16* __restrict__ tH,
                         u16* __restrict__ gHi, u16* __restrict__ wHi,
                         int* __restrict__ pMax, int* __restrict__ pMin) {
  const int b = blockIdx.x;
  if (b < 4096) {  // init 128x8192 partial keys
    const int i = b * 256 + threadIdx.x;
    pMax[i] = INT_MIN;
    pMin[i] = INT_MAX;
  }
  if (b < 2048) {
    const int lane = threadIdx.x & 63;
    const int wid  = threadIdx.x >> 6;
    const int row  = b * 4 + wid;
    const float* x = text + row * TDIM;
    float v[6];
    float ss = 0.f;
#pragma unroll
    for (int q = 0; q < 6; ++q) { v[q] = x[lane + q * 64]; ss += v[q] * v[q]; }
#pragma unroll
    for (int m = 1; m < 64; m <<= 1) ss += __shfl_xor(ss, m);
    const float scale = 1.0f / fmaxf(sqrtf(ss), 1e-12f);
#pragma unroll
    for (int q = 0; q < 6; ++q) {
      _Float16 h = (_Float16)(v[q] * scale);
      tH[row * TDIM + lane + q * 64] = *(u16*)&h;
    }
  } else {
    const int i = (b - 2048) * 256 + threadIdx.x;
    if (i < 524288) {
      float4 v = ((const float4*)graph)[i];
      ushort4 o; o.x = f2bf(v.x); o.y = f2bf(v.y); o.z = f2bf(v.z); o.w = f2bf(v.w);
      ((ushort4*)gHi)[i] = o;
    } else {
      int j = i - 524288;
      if (j < 24576) {
        float4 v = ((const float4*)W)[j];
        ushort4 o; o.x = f2bf(v.x); o.y = f2bf(v.y); o.z = f2bf(v.z); o.w = f2bf(v.w);
        ((ushort4*)wHi)[j] = o;
      }
    }
  }
}

// ---------- 2. fused simk + gemm1 (unchanged from r16: 53.5 us measured) ----------
__global__ __launch_bounds__(256, 4) void simgemm(const u16* __restrict__ tH,
                                                  const u16* __restrict__ gHi,
                                                  const u16* __restrict__ wHi,
                                                  const float* __restrict__ bias,
                                                  float* __restrict__ g,
                                                  int* __restrict__ pMax,
                                                  int* __restrict__ pMin) {
  __shared__ u16 sA[8192];   // sim: 128 rows x 64 | gemm: 128 x 32 (half used)
  __shared__ u16 sB[8192];
  const int tid = threadIdx.x;
  const int lane = tid & 63, wid = tid >> 6;
  const int l15 = lane & 15, l4 = lane >> 4;
  const int wrb = (wid >> 1) * 64, wcb = (wid & 1) * 64;

  if (blockIdx.x < 192) {
    // ================= gemm1 path =================
    const int iBase = (blockIdx.x & 63) * 128, jBase = (blockIdx.x >> 6) * 128;
    const int sRow = tid >> 2, sS = (tid & 3) * 8;
    f32x4 acc[4][4];
#pragma unroll
    for (int i = 0; i < 4; ++i)
#pragma unroll
      for (int j = 0; j < 4; ++j) acc[i][j] = (f32x4){0.f, 0.f, 0.f, 0.f};

    for (int ks = 0; ks < GDIM / 32; ++ks) {
      const int kB = ks * 32;
      __syncthreads();
      gload16(&sA[tid * 8],        gHi + (size_t)(iBase + sRow) * GDIM + kB + sS);
      gload16(&sA[2048 + tid * 8], gHi + (size_t)(iBase + 64 + sRow) * GDIM + kB + sS);
      gload16(&sB[tid * 8],        wHi + (size_t)(jBase + sRow) * GDIM + kB + sS);
      gload16(&sB[2048 + tid * 8], wHi + (size_t)(jBase + 64 + sRow) * GDIM + kB + sS);
      __syncthreads();
      short8 a[4], b[4];
#pragma unroll
      for (int f = 0; f < 4; ++f) {
        a[f] = *(const short8*)&sA[(wrb + f * 16 + l15) * 32 + l4 * 8];
        b[f] = *(const short8*)&sB[(wcb + f * 16 + l15) * 32 + l4 * 8];
      }
#pragma unroll
      for (int i = 0; i < 4; ++i)
#pragma unroll
        for (int j = 0; j < 4; ++j)
          acc[i][j] = __builtin_amdgcn_mfma_f32_16x16x32_bf16(a[i], b[j], acc[i][j], 0, 0, 0);
    }
#pragma unroll
    for (int j = 0; j < 4; ++j) {
      const int col = jBase + wcb + j * 16 + l15;
      const float bv = bias[col];
#pragma unroll
      for (int i = 0; i < 4; ++i)
#pragma unroll
        for (int r = 0; r < 4; ++r) {
          const int row = iBase + wrb + i * 16 + l4 * 4 + r;
          g[(size_t)row * TDIM + col] = acc[i][j][r] + bv;
        }
    }
    return;
  }

  // ================= sim path =================
  const int b = blockIdx.x - 192;
  const int id = (b & 7) * 260 + (b >> 3);     // XCD-chunked bijective (2080 = 8*260)

  // supertile-major decode (8x8-panel supertiles over 64 panels)
  int SI = 0, rem = id;
  for (; SI < 8; ++SI) {
    const int rc = 36 + (7 - SI) * 64;
    if (rem < rc) break;
    rem -= rc;
  }
  int bi, bj;
  if (rem < 36) {            // diagonal supertile: upper-tri 8x8
    int li = 0, r2 = rem;
    for (; li < 8; ++li) { const int c = 8 - li; if (r2 < c) break; r2 -= c; }
    bi = SI * 8 + li;
    bj = SI * 8 + li + r2;
  } else {                   // off-diagonal supertile: full 8x8
    const int r2 = rem - 36;
    const int sj = SI + 1 + (r2 >> 6);
    const int l = r2 & 63;
    bi = SI * 8 + (l >> 3);
    bj = sj * 8 + (l & 7);
  }
  const int rBase = bi * 128, cBase = bj * 128;
  const bool diagT = (bi == bj);

  const int sR = tid >> 3;                      // staging row 0..31
  const int ch = tid & 7;                       // staging chunk 0..7
  const int cg = ((ch ^ (sR & 7)) * 8);         // pre-swizzled source col offset
  const u16* aS = tH + (size_t)rBase * TDIM;
  const u16* bS = tH + (size_t)cBase * TDIM;

  f32x4 acc[4][4];
#pragma unroll
  for (int i = 0; i < 4; ++i)
#pragma unroll
    for (int j = 0; j < 4; ++j) acc[i][j] = (f32x4){0.f, 0.f, 0.f, 0.f};

  for (int t = 0; t < 6; ++t) {
    const int kB = t * 64;
    __syncthreads();   // prior step's ds_reads done -> safe to overwrite
#pragma unroll
    for (int r = 0; r < 4; ++r) {
      gload16(&sA[r * 2048 + tid * 8], aS + (size_t)(sR + 32 * r) * TDIM + kB + cg);
      gload16(&sB[r * 2048 + tid * 8], bS + (size_t)(sR + 32 * r) * TDIM + kB + cg);
    }
    __syncthreads();   // drains vmcnt(0): staged data visible

#pragma unroll
    for (int kk = 0; kk < 2; ++kk) {
      half8 a[4], b8[4];
#pragma unroll
      for (int f = 0; f < 4; ++f) {
        const int ar = wrb + f * 16 + l15;
        const int br = wcb + f * 16 + l15;
        a[f]  = *(const half8*)&sA[ar * 64 + (((kk * 4 + l4) ^ (ar & 7)) * 8)];
        b8[f] = *(const half8*)&sB[br * 64 + (((kk * 4 + l4) ^ (br & 7)) * 8)];
      }
      __builtin_amdgcn_s_setprio(1);
#pragma unroll
      for (int i = 0; i < 4; ++i)
#pragma unroll
        for (int j = 0; j < 4; ++j)
          acc[i][j] = __builtin_amdgcn_mfma_f32_16x16x32_f16(a[i], b8[j], acc[i][j], 0, 0, 0);
      __builtin_amdgcn_s_setprio(0);
    }
  }

  // ---- slim epilogue: merge buffers aliased on staging LDS ----
  int* sMd = (int*)&sA[0];     // [128] direct max
  int* sNd = (int*)&sA[256];   // [128] direct min
  int* sMt = (int*)&sA[512];   // [128] transposed max
  int* sNt = (int*)&sA[768];   // [128] transposed min

  __syncthreads();  // all waves past LDS staging reads -> safe to reuse sA
  if (tid < 128) {
    sMd[tid] = INT_MIN; sNd[tid] = INT_MAX;
  } else {
    sMt[tid - 128] = INT_MIN; sNt[tid - 128] = INT_MAX;
  }
  __syncthreads();

  // direct keys: per (i,r) fold j's -> 16-lane reduce -> one LDS atomic
#pragma unroll
  for (int i = 0; i < 4; ++i)
#pragma unroll
    for (int r = 0; r < 4; ++r) {
      const int grow = rBase + wrb + i * 16 + l4 * 4 + r;
      int km = INT_MIN, kn = INT_MAX;
#pragma unroll
      for (int j = 0; j < 4; ++j) {
        const int cIdx = cBase + wcb + j * 16 + l15;
        const int qv = (int)(acc[i][j][r] * 131072.0f);
        int kmv = qv * 8192 + (8191 - cIdx);
        int knv = qv * 8192 + cIdx;
        if (diagT && grow == cIdx) { kmv = 8191 - cIdx; knv = INT_MAX; }
        km = max(km, kmv);
        kn = min(kn, knv);
      }
#pragma unroll
      for (int m = 1; m < 16; m <<= 1) {
        km = max(km, __shfl_xor(km, m));
        kn = min(kn, __shfl_xor(kn, m));
      }
      if (l15 == 0) {
        atomicMax(&sMd[wrb + i * 16 + l4 * 4 + r], km);
        atomicMin(&sNd[wrb + i * 16 + l4 * 4 + r], kn);
      }
    }

  // transposed keys: per j fold (i,r) -> 4-group reduce -> one LDS atomic
#pragma unroll
  for (int j = 0; j < 4; ++j) {
    const int cIdx = cBase + wcb + j * 16 + l15;
    int km = INT_MIN, kn = INT_MAX;
#pragma unroll
    for (int i = 0; i < 4; ++i)
#pragma unroll
      for (int r = 0; r < 4; ++r) {
        const int grow = rBase + wrb + i * 16 + l4 * 4 + r;
        const int qv = (int)(acc[i][j][r] * 131072.0f);
        int kmv = qv * 8192 + (8191 - grow);
        int knv = qv * 8192 + grow;
        if (diagT && grow == cIdx) { kmv = 8191 - grow; knv = INT_MAX; }
        km = max(km, kmv);
        kn = min(kn, knv);
      }
    km = max(km, __shfl_xor(km, 16)); kn = min(kn, __shfl_xor(kn, 16));
    km = max(km, __shfl_xor(km, 32)); kn = min(kn, __shfl_xor(kn, 32));
    if (l4 == 0) {
      atomicMax(&sMt[wcb + j * 16 + l15], km);
      atomicMin(&sNt[wcb + j * 16 + l15], kn);
    }
  }
  __syncthreads();

  // coalesced line-exclusive store: p[chunk][row], 512B run per direction
  if (tid < 128) {
    pMax[(size_t)bj * BATCH + rBase + tid] = sMd[tid];
    pMin[(size_t)bj * BATCH + rBase + tid] = sNd[tid];
  } else {
    const int t2 = tid - 128;
    pMax[(size_t)(64 + bi) * BATCH + cBase + t2] = sMt[t2];
    pMin[(size_t)(64 + bi) * BATCH + cBase + t2] = sNt[t2];
  }
}

// ---------- 3. merge partials: thread = row, loop = chunk (coalesced) ----------
__global__ void merge_keys(const int* __restrict__ pMax, const int* __restrict__ pMin,
                           int* __restrict__ posIdx, int* __restrict__ negIdx) {
  const int row = blockIdx.x * 256 + threadIdx.x;
  int km = INT_MIN, kn = INT_MAX;
#pragma unroll 8
  for (int c = 0; c < 128; ++c) {
    km = max(km, pMax[(size_t)c * BATCH + row]);
    kn = min(kn, pMin[(size_t)c * BATCH + row]);
  }
  posIdx[row] = 8191 - (km & 8191);
  negIdx[row] = kn & 8191;
}

// ---------- 4. per-row triplet loss from raw g (norm fused via cosine) ----------
__global__ void loss_rows(const float* __restrict__ g, const int* __restrict__ posIdx,
                          const int* __restrict__ negIdx, float* __restrict__ losses) {
  const int lane = threadIdx.x & 63;
  const int wid  = threadIdx.x >> 6;
  const int row  = blockIdx.x * 4 + wid;
  const int pos = posIdx[row];
  const int neg = negIdx[row];
  const float* ga = g + (size_t)row * TDIM;
  const float* gp = g + (size_t)pos * TDIM;
  const float* gn = g + (size_t)neg * TDIM;
  float ssa = 0.f, ssp = 0.f, ssn = 0.f, dap = 0.f, dan = 0.f;
#pragma unroll
  for (int q = 0; q < 6; ++q) {
    const int o = lane + q * 64;
    const float a = ga[o], p = gp[o], n = gn[o];
    ssa += a * a; ssp += p * p; ssn += n * n;
    dap += a * p; dan += a * n;
  }
#pragma unroll
  for (int m = 1; m < 64; m <<= 1) {
    ssa += __shfl_xor(ssa, m);
    ssp += __shfl_xor(ssp, m);
    ssn += __shfl_xor(ssn, m);
    dap += __shfl_xor(dap, m);
    dan += __shfl_xor(dan, m);
  }
  if (lane == 0) {
    const float pd = 2.0f - 2.0f * dap / sqrtf(ssa * ssp);
    const float nd = 2.0f - 2.0f * dan / sqrtf(ssa * ssn);
    losses[row] = fmaxf(pd - nd + 0.5f, 0.0f);
  }
}

// ---------- 5. deterministic mean ----------
__global__ void final_reduce(const float* __restrict__ losses, float* __restrict__ out) {
  __shared__ float red[256];
  float s = 0.f;
  for (int i = threadIdx.x; i < BATCH; i += 256) s += losses[i];
  red[threadIdx.x] = s;
  __syncthreads();
  for (int w = 128; w > 0; w >>= 1) {
    if (threadIdx.x < w) red[threadIdx.x] += red[threadIdx.x + w];
    __syncthreads();
  }
  if (threadIdx.x == 0) out[0] = red[0] * (1.0f / (float)BATCH);
}

extern "C" void kernel_launch(void* const* d_in, const int* in_sizes, int n_in,
                              void* d_out, int out_size, void* d_ws, size_t ws_size,
                              hipStream_t stream) {
  const float* graph = (const float*)d_in[0];
  const float* text  = (const float*)d_in[1];
  const float* W     = (const float*)d_in[2];
  const float* bias  = (const float*)d_in[3];
  float* out = (float*)d_out;
  char* ws = (char*)d_ws;

  u16*  tH     = (u16*)(ws);                 // 8192*384*2  = 6291456
  u16*  gHi    = (u16*)(ws + 6291456);       // 8192*256*2  = 4194304
  u16*  wHi    = (u16*)(ws + 10485760);      // 384*256*2   = 196608
  float* g     = (float*)(ws + 10682368);    // 8192*384*4  = 12582912
  int*  pMax   = (int*)(ws + 23265280);      // 128*8192*4  = 4194304
  int*  pMin   = (int*)(ws + 27459584);      // 4194304
  float* losses = (float*)(ws + 31653888);   // 32768
  int*  posIdx = (int*)(ws + 31686656);      // 32768
  int*  negIdx = (int*)(ws + 31719424);      // 32768

  prep_all<<<dim3(4192), dim3(256), 0, stream>>>(text, graph, W, tH, gHi, wHi, pMax, pMin);
  simgemm<<<dim3(2272), dim3(256), 0, stream>>>(tH, gHi, wHi, bias, g, pMax, pMin);
  merge_keys<<<dim3(32), dim3(256), 0, stream>>>(pMax, pMin, posIdx, negIdx);
  loss_rows<<<dim3(2048), dim3(256), 0, stream>>>(g, posIdx, negIdx, losses);
  final_reduce<<<dim3(1), dim3(256), 0, stream>>>(losses, out);
}